// Round 9
// baseline (48.220 us; speedup 1.0000x reference)
//
#include <hip/hip_runtime.h>

#define E 128
#define Fb 32
#define TSH 136    // u16 stride per LDS table row (272 B)
#define ROWB 272   // table row byte stride

__device__ inline float bf2f(unsigned short u) {
    union { unsigned int i; float f; } x;
    x.i = ((unsigned int)u) << 16;
    return x.f;
}

// monotone bijection f32 -> u32 (ascending), finite values
__device__ inline unsigned int sortable(float f) {
    union { float f; unsigned int u; } x;
    x.f = f;
    unsigned int u = x.u;
    return (u & 0x80000000u) ? ~u : (u | 0x80000000u);
}

// ---------------- Kernel 1: table (blocks 0..63) + ranks (blocks 64..319) ---
// (identical to round 8)
__global__ __launch_bounds__(256) void spearman_prep(
        const float* __restrict__ de,
        unsigned char* __restrict__ ranks,
        unsigned char* __restrict__ ranksT2,
        unsigned short* __restrict__ table) {
    const int tid = threadIdx.x;

    if (blockIdx.x < 64) {
        __shared__ float rcp[E];
        if (tid < E) rcp[tid] = 1.0f / (float)(tid + 1);
        __syncthreads();
        int idx = (int)blockIdx.x * 256 + tid;
        int a = idx >> 7, c = idx & 127;
        float sa = 0.f, sc = 0.f, g = 0.f;
#pragma unroll 16
        for (int u = 0; u < E; ++u) {
            float wa = rcp[abs(u - a)];
            float wc = rcp[abs(u - c)];
            sa += wa;
            sc += wc;
            g += wa * wc;
        }
        float t = g - sa * sc * (1.0f / (float)(E - 1));
        union { float f; unsigned int i; } x;
        x.f = t;
        unsigned int r = (x.i + 0x7FFFu + ((x.i >> 16) & 1u)) >> 16;  // RNE bf16
        table[idx] = (unsigned short)r;
        return;
    }

    __shared__ __align__(16) unsigned char rt[16][128];  // 2 KB
    const int bid = (int)blockIdx.x - 64;
    const int b = bid >> 1, fh = bid & 1;
    const int wv = tid >> 6, lane = tid & 63;
    const int fbase = fh * 16 + wv * 4;

    const float4 vA = *(const float4*)(de + ((size_t)(b * E + lane)) * Fb + fbase);
    const float4 vB = *(const float4*)(de + ((size_t)(b * E + lane + 64)) * Fb + fbase);

    unsigned long long kA[4], kB[4];
    kA[0] = ((unsigned long long)sortable(vA.x) << 7) | (unsigned)lane;
    kA[1] = ((unsigned long long)sortable(vA.y) << 7) | (unsigned)lane;
    kA[2] = ((unsigned long long)sortable(vA.z) << 7) | (unsigned)lane;
    kA[3] = ((unsigned long long)sortable(vA.w) << 7) | (unsigned)lane;
    kB[0] = ((unsigned long long)sortable(vB.x) << 7) | (unsigned)(lane + 64);
    kB[1] = ((unsigned long long)sortable(vB.y) << 7) | (unsigned)(lane + 64);
    kB[2] = ((unsigned long long)sortable(vB.z) << 7) | (unsigned)(lane + 64);
    kB[3] = ((unsigned long long)sortable(vB.w) << 7) | (unsigned)(lane + 64);

    int c0[4] = {0, 0, 0, 0}, c1[4] = {0, 0, 0, 0};
#pragma unroll
    for (int j = 0; j < 64; ++j) {
#pragma unroll
        for (int fi = 0; fi < 4; ++fi) {
            unsigned int lo = (unsigned int)__builtin_amdgcn_readlane((int)(unsigned int)kA[fi], j);
            unsigned int hi = (unsigned int)__builtin_amdgcn_readlane((int)(unsigned int)(kA[fi] >> 32), j);
            unsigned long long cand = ((unsigned long long)hi << 32) | lo;
            c0[fi] += (int)(cand < kA[fi]);
            c1[fi] += (int)(cand < kB[fi]);
        }
    }
#pragma unroll
    for (int j = 0; j < 64; ++j) {
#pragma unroll
        for (int fi = 0; fi < 4; ++fi) {
            unsigned int lo = (unsigned int)__builtin_amdgcn_readlane((int)(unsigned int)kB[fi], j);
            unsigned int hi = (unsigned int)__builtin_amdgcn_readlane((int)(unsigned int)(kB[fi] >> 32), j);
            unsigned long long cand = ((unsigned long long)hi << 32) | lo;
            c0[fi] += (int)(cand < kA[fi]);
            c1[fi] += (int)(cand < kB[fi]);
        }
    }

#pragma unroll
    for (int fi = 0; fi < 4; ++fi) {
        rt[wv * 4 + fi][lane] = (unsigned char)c0[fi];
        rt[wv * 4 + fi][lane + 64] = (unsigned char)c1[fi];
    }
    __syncthreads();

    if (tid < 128) {
        const int f = tid >> 3, e0 = (tid & 7) * 16;
        *(uint4*)(ranks + ((size_t)b * Fb + fh * 16 + f) * E + e0) = *(const uint4*)&rt[f][e0];
        const int e = tid;
        unsigned int w[4];
#pragma unroll
        for (int g = 0; g < 4; ++g) {
            w[g] = ((unsigned)rt[g * 4 + 0][e] * 2)
                 | (((unsigned)rt[g * 4 + 1][e] * 2) << 8)
                 | (((unsigned)rt[g * 4 + 2][e] * 2) << 16)
                 | (((unsigned)rt[g * 4 + 3][e] * 2) << 24);
        }
        *(uint4*)(ranksT2 + ((size_t)b * E + e) * Fb + fh * 16) =
            make_uint4(w[0], w[1], w[2], w[3]);
    }
}

// ---------------- Kernel 2: out[b,j,k] = mean_f T[rj, rk], symmetric -------
// (identical to round 8; launched 3x this round as an idempotent timing probe)
__global__ __launch_bounds__(256, 3) void spearman_acc(
        const unsigned char* __restrict__ ranks,
        const unsigned char* __restrict__ ranksT2,
        const unsigned short* __restrict__ table,
        float* __restrict__ out) {
    __shared__ __align__(16) unsigned short tbl[E * TSH];  // 34816 B
    __shared__ __align__(16) float trans[64 * 33];         // 8448 B
    const int tid = threadIdx.x;
    const int b = blockIdx.x / 6;
    const int t = blockIdx.x % 6;
    const int ti  = (t < 4) ? (t >> 1) : (t - 2);   // {0,0,1,1,2,3}
    const int cb  = (t < 4) ? (t & 1) : 1;          // {0,1,0,1,1,1}
    const int mir = (t < 4) ? (t & 1) : 0;          // {0,1,0,1,0,0}
    const int j0 = ti * 32, k0 = cb * 64;

    const int wave = tid >> 6, lane = tid & 63;
    const int k = k0 + lane;
    const unsigned char* rb  = ranks   + b * (Fb * E);
    const unsigned char* rbT = ranksT2 + b * (Fb * E);

    int rk2[Fb];
#pragma unroll
    for (int f4 = 0; f4 < 8; ++f4) {
        uchar4 qv = *(const uchar4*)&rbT[k * Fb + f4 * 4];
        rk2[f4 * 4 + 0] = (int)qv.x;
        rk2[f4 * 4 + 1] = (int)qv.y;
        rk2[f4 * 4 + 2] = (int)qv.z;
        rk2[f4 * 4 + 3] = (int)qv.w;
    }

    int rj272[4];
#pragma unroll
    for (int rp = 0; rp < 4; ++rp) {
        int fl = rp * 8 + (lane >> 3);
        int row = j0 + wave + 4 * (lane & 7);
        rj272[rp] = (int)rb[fl * E + row] * ROWB;
    }

    const uint4* t16 = (const uint4*)table;
#pragma unroll
    for (int i = 0; i < 8; ++i) {
        int idx = tid + i * 256;
        uint4 v = t16[idx];
        int a = idx >> 4;
        int c = (idx & 15) * 8;
        *(uint4*)&tbl[a * TSH + c] = v;
    }
    __syncthreads();

    float acc[8] = {0.f, 0.f, 0.f, 0.f, 0.f, 0.f, 0.f, 0.f};
#pragma unroll
    for (int f = 0; f < Fb; ++f) {
        const int rg = f >> 3, li = (f & 7) << 3;
        const int ck = rk2[f];
#pragma unroll
        for (int g = 0; g < 8; ++g) {
            int ro = __builtin_amdgcn_readlane(rj272[rg], li | g);
            acc[g] += bf2f(*(const unsigned short*)((const char*)tbl + ro + ck));
        }
    }

    const float s = 1.0f / (float)Fb;
    float* ob = out + b * (E * E);
#pragma unroll
    for (int g = 0; g < 8; ++g)
        ob[(j0 + wave + 4 * g) * E + k] = acc[g] * s;

    if (mir) {
#pragma unroll
        for (int g = 0; g < 8; ++g)
            trans[lane * 33 + (wave + 4 * g)] = acc[g] * s;
        __syncthreads();
#pragma unroll
        for (int g = 0; g < 8; ++g) {
            int rr = (tid >> 5) + 8 * g;
            int cc = tid & 31;
            ob[(k0 + rr) * E + (j0 + cc)] = trans[rr * 33 + cc];
        }
    }
}

extern "C" void kernel_launch(void* const* d_in, const int* in_sizes, int n_in,
                              void* d_out, int out_size, void* d_ws, size_t ws_size,
                              hipStream_t stream) {
    const float* de = (const float*)d_in[0];     // [128,128,32] f32
    float* out = (float*)d_out;                  // [128,128,128] f32

    const int B = 128;
    unsigned char* ranks   = (unsigned char*)d_ws;                         // 512KB
    unsigned char* ranksT2 = (unsigned char*)d_ws + (size_t)B * Fb * E;    // 512KB
    unsigned short* table  = (unsigned short*)((char*)d_ws + 2 * (size_t)B * Fb * E);  // 32KB

    spearman_prep<<<64 + B * 2, 256, 0, stream>>>(de, ranks, ranksT2, table);
    // TIMING PROBE: acc launched 3x (idempotent, bitwise-identical rewrites).
    // (dur_us - 27.87)/2 = acc_exec + per-launch overhead.
    spearman_acc<<<B * 6, 256, 0, stream>>>(ranks, ranksT2, table, out);
    spearman_acc<<<B * 6, 256, 0, stream>>>(ranks, ranksT2, table, out);
    spearman_acc<<<B * 6, 256, 0, stream>>>(ranks, ranksT2, table, out);
}

// Round 10
// 26.802 us; speedup vs baseline: 1.7991x; 1.7991x over previous
//
#include <hip/hip_runtime.h>

#define E 128
#define Fb 32
#define TSH 136    // u16 stride per LDS table row (272 B)
#define ROWB 272   // table row byte stride

__device__ inline float bf2f(unsigned short u) {
    union { unsigned int i; float f; } x;
    x.i = ((unsigned int)u) << 16;
    return x.f;
}

// monotone bijection f32 -> u32 (ascending), finite values
__device__ inline unsigned int sortable(float f) {
    union { float f; unsigned int u; } x;
    x.f = f;
    unsigned int u = x.u;
    return (u & 0x80000000u) ? ~u : (u | 0x80000000u);
}

// ------- Kernel 1: ranks (blocks 0..511) + table (blocks 512..575) ---------
// ranks: stable rank = #{j: key_j < key_e}, key = (sortable(x)<<7)|e.
//        Block = (batch b, freq-quarter q): 8 freqs; wave owns 2 freqs;
//        lane holds electrodes lane and lane+64. 512 blocks ~= 2/CU.
// table: T[a,c] = sum_u rcp(|u-a|)*rcp(|u-c|) - S(a)S(c)/127, bf16 RNE.
__global__ __launch_bounds__(256) void spearman_prep(
        const float* __restrict__ de,
        unsigned char* __restrict__ ranks,
        unsigned char* __restrict__ ranksT2,
        unsigned short* __restrict__ table) {
    const int tid = threadIdx.x;

    if (blockIdx.x >= 512) {
        // ---- table blocks: 256 entries each (2 rows of T) ----
        __shared__ float rcp[E];
        if (tid < E) rcp[tid] = 1.0f / (float)(tid + 1);
        __syncthreads();
        int idx = ((int)blockIdx.x - 512) * 256 + tid;
        int a = idx >> 7, c = idx & 127;
        float sa = 0.f, sc = 0.f, g = 0.f;
#pragma unroll 16
        for (int u = 0; u < E; ++u) {
            float wa = rcp[abs(u - a)];
            float wc = rcp[abs(u - c)];
            sa += wa;
            sc += wc;
            g += wa * wc;
        }
        float t = g - sa * sc * (1.0f / (float)(E - 1));
        union { float f; unsigned int i; } x;
        x.f = t;
        unsigned int r = (x.i + 0x7FFFu + ((x.i >> 16) & 1u)) >> 16;  // RNE bf16
        table[idx] = (unsigned short)r;
        return;
    }

    // ---- rank blocks ----
    __shared__ __align__(16) unsigned char rt[8][128];  // 1 KB
    const int b = (int)blockIdx.x >> 2;
    const int q = (int)blockIdx.x & 3;
    const int wv = tid >> 6, lane = tid & 63;
    const int f0 = q * 8 + wv * 2;   // wave owns f0, f0+1

    const float2 vA = *(const float2*)(de + ((size_t)(b * E + lane)) * Fb + f0);
    const float2 vB = *(const float2*)(de + ((size_t)(b * E + lane + 64)) * Fb + f0);

    unsigned long long kA[2], kB[2];
    kA[0] = ((unsigned long long)sortable(vA.x) << 7) | (unsigned)lane;
    kA[1] = ((unsigned long long)sortable(vA.y) << 7) | (unsigned)lane;
    kB[0] = ((unsigned long long)sortable(vB.x) << 7) | (unsigned)(lane + 64);
    kB[1] = ((unsigned long long)sortable(vB.y) << 7) | (unsigned)(lane + 64);

    int c0[2] = {0, 0}, c1[2] = {0, 0};
#pragma unroll
    for (int j = 0; j < 64; ++j) {
#pragma unroll
        for (int fi = 0; fi < 2; ++fi) {
            unsigned int lo = (unsigned int)__builtin_amdgcn_readlane((int)(unsigned int)kA[fi], j);
            unsigned int hi = (unsigned int)__builtin_amdgcn_readlane((int)(unsigned int)(kA[fi] >> 32), j);
            unsigned long long cand = ((unsigned long long)hi << 32) | lo;
            c0[fi] += (int)(cand < kA[fi]);
            c1[fi] += (int)(cand < kB[fi]);
        }
    }
#pragma unroll
    for (int j = 0; j < 64; ++j) {
#pragma unroll
        for (int fi = 0; fi < 2; ++fi) {
            unsigned int lo = (unsigned int)__builtin_amdgcn_readlane((int)(unsigned int)kB[fi], j);
            unsigned int hi = (unsigned int)__builtin_amdgcn_readlane((int)(unsigned int)(kB[fi] >> 32), j);
            unsigned long long cand = ((unsigned long long)hi << 32) | lo;
            c0[fi] += (int)(cand < kA[fi]);
            c1[fi] += (int)(cand < kB[fi]);
        }
    }

#pragma unroll
    for (int fi = 0; fi < 2; ++fi) {
        rt[wv * 2 + fi][lane] = (unsigned char)c0[fi];
        rt[wv * 2 + fi][lane + 64] = (unsigned char)c1[fi];
    }
    __syncthreads();

    // coalesced dumps (ranksT2 holds rank*2 = table byte offsets)
    if (tid < 64) {
        const int f = tid >> 3, e0 = (tid & 7) * 16;   // 8 f-rows x 8 chunks
        *(uint4*)(ranks + ((size_t)b * Fb + q * 8 + f) * E + e0) = *(const uint4*)&rt[f][e0];
    }
    if (tid < 128) {
        const int e = tid;
        unsigned int w[2];
#pragma unroll
        for (int g = 0; g < 2; ++g) {
            w[g] = ((unsigned)rt[g * 4 + 0][e] * 2)
                 | (((unsigned)rt[g * 4 + 1][e] * 2) << 8)
                 | (((unsigned)rt[g * 4 + 2][e] * 2) << 16)
                 | (((unsigned)rt[g * 4 + 3][e] * 2) << 24);
        }
        *(uint2*)(ranksT2 + ((size_t)b * E + e) * Fb + q * 8) = make_uint2(w[0], w[1]);
    }
}

// ---------------- Kernel 2: out[b,j,k] = mean_f T[rj, rk], symmetric -------
// Round-8 body, but trans ALIASES tbl's LDS (tbl is dead after the gather
// loop; mir branch is block-uniform so the extra __syncthreads is legal).
// LDS 34.8KB -> 4 blocks/CU = 16 waves/CU.
__global__ __launch_bounds__(256, 4) void spearman_acc(
        const unsigned char* __restrict__ ranks,
        const unsigned char* __restrict__ ranksT2,
        const unsigned short* __restrict__ table,
        float* __restrict__ out) {
    __shared__ __align__(16) char smem[E * TSH * 2];       // 34816 B
    unsigned short* tbl = (unsigned short*)smem;           // [E][TSH]
    float* trans = (float*)smem;                           // 64*33 f32, aliases tbl
    const int tid = threadIdx.x;
    const int b = blockIdx.x / 6;
    const int t = blockIdx.x % 6;
    const int ti  = (t < 4) ? (t >> 1) : (t - 2);   // {0,0,1,1,2,3}
    const int cb  = (t < 4) ? (t & 1) : 1;          // {0,1,0,1,1,1}
    const int mir = (t < 4) ? (t & 1) : 0;          // {0,1,0,1,0,0}
    const int j0 = ti * 32, k0 = cb * 64;

    const int wave = tid >> 6, lane = tid & 63;
    const int k = k0 + lane;
    const unsigned char* rb  = ranks   + b * (Fb * E);
    const unsigned char* rbT = ranksT2 + b * (Fb * E);

    int rk2[Fb];
#pragma unroll
    for (int f4 = 0; f4 < 8; ++f4) {
        uchar4 qv = *(const uchar4*)&rbT[k * Fb + f4 * 4];
        rk2[f4 * 4 + 0] = (int)qv.x;
        rk2[f4 * 4 + 1] = (int)qv.y;
        rk2[f4 * 4 + 2] = (int)qv.z;
        rk2[f4 * 4 + 3] = (int)qv.w;
    }

    int rj272[4];
#pragma unroll
    for (int rp = 0; rp < 4; ++rp) {
        int fl = rp * 8 + (lane >> 3);
        int row = j0 + wave + 4 * (lane & 7);
        rj272[rp] = (int)rb[fl * E + row] * ROWB;
    }

    const uint4* t16 = (const uint4*)table;
#pragma unroll
    for (int i = 0; i < 8; ++i) {
        int idx = tid + i * 256;
        uint4 v = t16[idx];
        int a = idx >> 4;
        int c = (idx & 15) * 8;
        *(uint4*)&tbl[a * TSH + c] = v;
    }
    __syncthreads();

    float acc[8] = {0.f, 0.f, 0.f, 0.f, 0.f, 0.f, 0.f, 0.f};
#pragma unroll
    for (int f = 0; f < Fb; ++f) {
        const int rg = f >> 3, li = (f & 7) << 3;
        const int ck = rk2[f];
#pragma unroll
        for (int g = 0; g < 8; ++g) {
            int ro = __builtin_amdgcn_readlane(rj272[rg], li | g);
            acc[g] += bf2f(*(const unsigned short*)((const char*)tbl + ro + ck));
        }
    }

    const float s = 1.0f / (float)Fb;
    float* ob = out + b * (E * E);
#pragma unroll
    for (int g = 0; g < 8; ++g)
        ob[(j0 + wave + 4 * g) * E + k] = acc[g] * s;

    if (mir) {
        __syncthreads();   // all gathers done before trans overwrites tbl
#pragma unroll
        for (int g = 0; g < 8; ++g)
            trans[lane * 33 + (wave + 4 * g)] = acc[g] * s;
        __syncthreads();
#pragma unroll
        for (int g = 0; g < 8; ++g) {
            int rr = (tid >> 5) + 8 * g;
            int cc = tid & 31;
            ob[(k0 + rr) * E + (j0 + cc)] = trans[rr * 33 + cc];
        }
    }
}

extern "C" void kernel_launch(void* const* d_in, const int* in_sizes, int n_in,
                              void* d_out, int out_size, void* d_ws, size_t ws_size,
                              hipStream_t stream) {
    const float* de = (const float*)d_in[0];     // [128,128,32] f32
    float* out = (float*)d_out;                  // [128,128,128] f32

    const int B = 128;
    unsigned char* ranks   = (unsigned char*)d_ws;                         // 512KB
    unsigned char* ranksT2 = (unsigned char*)d_ws + (size_t)B * Fb * E;    // 512KB
    unsigned short* table  = (unsigned short*)((char*)d_ws + 2 * (size_t)B * Fb * E);  // 32KB

    spearman_prep<<<512 + 64, 256, 0, stream>>>(de, ranks, ranksT2, table);
    spearman_acc<<<B * 6, 256, 0, stream>>>(ranks, ranksT2, table, out);
}